// Round 8
// baseline (361.074 us; speedup 1.0000x reference)
//
#include <hip/hip_runtime.h>

// PseudoImageScatter: img[f, y, x] = pillar_features[p, f], last pillar wins.
// Pass 1: winner[y*W+x] = atomicMax(pillar idx)  (last-wins == max idx)
// Pass 2 (v8): plane-major, no LDS, no barriers. Block owns (plane f, span of
//   16384 cells) and writes 64 KiB CONTIGUOUS (16 sequential 4 KiB sweeps) —
//   fillBuffer-like long runs for DRAM row locality. R1-R7 all interleaved
//   ~65k 1KiB write streams across 64 planes and all tied at ~300 µs; the
//   write pattern is the one axis never varied.
//   Reads: winner span re-read once per plane (L2/L3-resident, HBM fetch 4MB
//   once); feature gather = 1 exec-masked scalar dword per occupied cell,
//   feat L3-resident; adjacent-f concurrent blocks share feat cache lines.

constexpr int H    = 1024;
constexpr int W    = 1024;
constexpr int HW   = H * W;
constexpr int NF   = 64;
constexpr int SPAN = 16384;         // cells per block (64 KiB of one plane)

__global__ void winner_kernel(const int* __restrict__ coords,
                              int* __restrict__ winner, int np) {
    int p = blockIdx.x * blockDim.x + threadIdx.x;
    if (p >= np) return;
    int y = coords[p * 3 + 1];
    int x = coords[p * 3 + 2];
    if ((unsigned)x < (unsigned)W && (unsigned)y < (unsigned)H) {
        atomicMax(winner + (y * W + x), p);   // device-scope, cross-XCD safe
    }
}

__global__ void __launch_bounds__(256) fill_kernel(const float* __restrict__ feat,
                                                   const int* __restrict__ winner,
                                                   float* __restrict__ out) {
    const int bid = blockIdx.x;
    const int f   = bid & 63;                 // plane; adjacent blocks share feat lines
    const int s   = bid >> 6;                 // span 0..63
    const int c0  = s * SPAN;
    const int t   = threadIdx.x;

    const int*   wbase = winner + c0;
    float*       obase = out + (size_t)f * HW + c0;

    // 16 sweeps x 1024 cells; each wave-instr: int4 winner load (coalesced),
    // <=4 exec-masked scalar feat gathers, float4 store (1 KiB/wave-instr,
    // sequential sweeps -> 64 KiB contiguous per block).
#pragma unroll 4
    for (int i = 0; i < SPAN / 1024; ++i) {
        const int c = i * 1024 + t * 4;
        int4 w = *(const int4*)(wbase + c);
        float4 v;
        v.x = (w.x >= 0) ? feat[(size_t)w.x * NF + f] : 0.0f;
        v.y = (w.y >= 0) ? feat[(size_t)w.y * NF + f] : 0.0f;
        v.z = (w.z >= 0) ? feat[(size_t)w.z * NF + f] : 0.0f;
        v.w = (w.w >= 0) ? feat[(size_t)w.w * NF + f] : 0.0f;
        *(float4*)(obase + c) = v;
    }
}

extern "C" void kernel_launch(void* const* d_in, const int* in_sizes, int n_in,
                              void* d_out, int out_size, void* d_ws, size_t ws_size,
                              hipStream_t stream) {
    const float* feat   = (const float*)d_in[0];
    const int*   coords = (const int*)d_in[1];
    float*       out    = (float*)d_out;
    int np = in_sizes[1] / 3;

    int* winner = (int*)d_ws;   // HW ints = 4 MiB scratch

    (void)hipMemsetAsync(winner, 0xFF, (size_t)HW * sizeof(int), stream);  // winner := -1
    winner_kernel<<<(np + 255) / 256, 256, 0, stream>>>(coords, winner, np);
    fill_kernel<<<NF * (HW / SPAN), 256, 0, stream>>>(feat, winner, out);
}

// Round 9
// 300.067 us; speedup vs baseline: 1.2033x; 1.2033x over previous
//
#include <hip/hip_runtime.h>

// PseudoImageScatter: img[f, y, x] = pillar_features[p, f], last pillar wins.
// Pass 1: winner[y*W+x] = atomicMax(pillar idx)  (last-wins == max idx)
// Pass 2 (v9): 1024-cell tiles, 8 passes x 8 features, 32 KiB LDS, 4 blocks/CU
//   (grid = 1024 = exactly 4 per CU). Read side identical in structure to R6
//   (zero-once LDS, exec-masked float4 row gather, each row loaded once);
//   write side now emits 4 KiB contiguous runs per plane per block (4x R6) —
//   clean test of the write-run-length theory (R8 tested it confounded by
//   64x gather amplification and regressed).

constexpr int H     = 1024;
constexpr int W     = 1024;
constexpr int HW    = H * W;
constexpr int NF    = 64;
constexpr int TILE  = 1024;          // cells per block
constexpr int FP    = 8;             // features per pass
constexpr int NPASS = NF / FP;       // 8

__global__ void winner_kernel(const int* __restrict__ coords,
                              int* __restrict__ winner, int np) {
    int p = blockIdx.x * blockDim.x + threadIdx.x;
    if (p >= np) return;
    int y = coords[p * 3 + 1];
    int x = coords[p * 3 + 2];
    if ((unsigned)x < (unsigned)W && (unsigned)y < (unsigned)H) {
        atomicMax(winner + (y * W + x), p);   // device-scope, cross-XCD safe
    }
}

__device__ __forceinline__ void stage8(const float4* __restrict__ row, int q,
                                       float* __restrict__ lds, int c) {
    float4 a = row[q * 2 + 0];
    float4 b = row[q * 2 + 1];
    lds[0 * TILE + c] = a.x;  lds[1 * TILE + c] = a.y;
    lds[2 * TILE + c] = a.z;  lds[3 * TILE + c] = a.w;
    lds[4 * TILE + c] = b.x;  lds[5 * TILE + c] = b.y;
    lds[6 * TILE + c] = b.z;  lds[7 * TILE + c] = b.w;
}

__global__ void __launch_bounds__(256, 4) fill_kernel(const float* __restrict__ feat,
                                                      const int* __restrict__ winner,
                                                      float* __restrict__ out) {
    __shared__ float lds[FP * TILE];          // 32 KiB, f-major

    const int base = blockIdx.x * TILE;
    const int t    = threadIdx.x;
    const int wv   = t >> 6;                  // wave 0..3
    const int l    = t & 63;                  // lane

    // Thread t owns cells t, t+256, t+512, t+768 (coalesced winner loads,
    // LDS-write bank = t%32 -> 2-way = free).
    const int w0 = winner[base + t];
    const int w1 = winner[base + t + 256];
    const int w2 = winner[base + t + 512];
    const int w3 = winner[base + t + 768];

    // Zero LDS once; empty columns are never written again, stay zero all passes.
    {
        float4 z = {0.0f, 0.0f, 0.0f, 0.0f};
#pragma unroll
        for (int j = 0; j < 8; ++j)
            *(float4*)&lds[j * 1024 + t * 4] = z;
    }
    __syncthreads();

    const float4* r0 = (const float4*)(feat + (size_t)max(w0, 0) * NF);
    const float4* r1 = (const float4*)(feat + (size_t)max(w1, 0) * NF);
    const float4* r2 = (const float4*)(feat + (size_t)max(w2, 0) * NF);
    const float4* r3 = (const float4*)(feat + (size_t)max(w3, 0) * NF);

    for (int q = 0; q < NPASS; ++q) {
        // ---- Phase A: exec-masked sparse gather (each row read once total).
        if (w0 >= 0) stage8(r0, q, lds, t);
        if (w1 >= 0) stage8(r1, q, lds, t + 256);
        if (w2 >= 0) stage8(r2, q, lds, t + 512);
        if (w3 >= 0) stage8(r3, q, lds, t + 768);
        __syncthreads();

        // ---- Phase B: wave wv writes planes wv*2, wv*2+1 of this pass;
        // per plane 4 chunks x 1 KiB = 4 KiB contiguous run per block.
#pragma unroll
        for (int pl = 0; pl < 2; ++pl) {
            const int floc = wv * 2 + pl;
            float* op = out + (size_t)(q * FP + floc) * HW + base;
#pragma unroll
            for (int ch = 0; ch < 4; ++ch) {
                float4 v = *(const float4*)&lds[floc * TILE + ch * 256 + l * 4];
                *(float4*)(op + ch * 256 + l * 4) = v;
            }
        }
        __syncthreads();   // B(q) must finish before A(q+1) overwrites columns
    }
}

extern "C" void kernel_launch(void* const* d_in, const int* in_sizes, int n_in,
                              void* d_out, int out_size, void* d_ws, size_t ws_size,
                              hipStream_t stream) {
    const float* feat   = (const float*)d_in[0];
    const int*   coords = (const int*)d_in[1];
    float*       out    = (float*)d_out;
    int np = in_sizes[1] / 3;

    int* winner = (int*)d_ws;   // HW ints = 4 MiB scratch

    (void)hipMemsetAsync(winner, 0xFF, (size_t)HW * sizeof(int), stream);  // winner := -1
    winner_kernel<<<(np + 255) / 256, 256, 0, stream>>>(coords, winner, np);
    fill_kernel<<<HW / TILE, 256, 0, stream>>>(feat, winner, out);
}